// Round 16
// baseline (117.951 us; speedup 1.0000x reference)
//
#include <hip/hip_runtime.h>
#include <cstdint>

#define HDIM 256
#define MT   256      // feature rows per block (4 waves x 64 rows)
#define BDW  16       // En rows per WAVE-PRIVATE window (one MFMA A-tile)
#define SPLITS 32
#define RPB  16       // rows per prep block (4 per wave)

typedef short bf16x8 __attribute__((ext_vector_type(8)));
typedef short bf16x4 __attribute__((ext_vector_type(4)));
typedef float f32x4  __attribute__((ext_vector_type(4)));

typedef const __attribute__((address_space(1))) short as1_short;
typedef __attribute__((address_space(3))) short as3_short;

// packed RNE f32->bf16 (r21-proven: -28% fused wall, absmax unchanged).
static __device__ __forceinline__ uint32_t cvt_pk_bf16(float lo, float hi) {
    uint32_t r;
    asm("v_cvt_pk_bf16_f32 %0, %1, %2" : "=v"(r) : "v"(lo), "v"(hi));
    return r;
}

// ---- prep (single dispatch):
//  blocks [0, nb_nrm)          : L2-normalize feature/ex_feature rows -> bf16,
//                                stored with XOR-16B-chunk swizzle; 4 rows/wave
//  blocks [nb_nrm, nb_nrm+128) : transpose class reps to Rt[32][D] (col C = 1.0
//                                -> intensity falls out of the echo GEMM)
__global__ __launch_bounds__(256) void prep_kernel(const float* __restrict__ fsrc,
                                                   const float* __restrict__ esrc,
                                                   const float* __restrict__ reps,
                                                   short* __restrict__ dst,
                                                   short* __restrict__ rt,
                                                   int N, int rows_total,
                                                   int D, int C, int nb_nrm) {
    __shared__ float lds[128][29];                    // +1 pad col
    const int tid = threadIdx.x;
    if ((int)blockIdx.x < nb_nrm) {
        int wv = tid >> 6;
        int lane = tid & 63;
        int row0 = blockIdx.x * RPB + wv * 4;
        #pragma unroll
        for (int rr = 0; rr < 4; ++rr) {
            int row = row0 + rr;
            if (row >= rows_total) continue;
            const float* src = (row < N) ? (fsrc + (size_t)row * HDIM)
                                         : (esrc + (size_t)(row - N) * HDIM);
            const float4 v = *(const float4*)(src + lane * 4);
            float ss = v.x * v.x + v.y * v.y + v.z * v.z + v.w * v.w;
            #pragma unroll
            for (int m = 1; m < 64; m <<= 1) ss += __shfl_xor(ss, m, 64);
            float scale = 1.0f / fmaxf(sqrtf(ss), 1e-12f);
            union { uint32_t u[2]; short4 s; } pk;
            pk.u[0] = cvt_pk_bf16(v.x * scale, v.y * scale);
            pk.u[1] = cvt_pk_bf16(v.z * scale, v.w * scale);
            int chunk = (lane >> 1) ^ (row & 7);      // swizzled 16B-chunk index
            *(short4*)(dst + (size_t)row * HDIM + chunk * 8 + (lane & 1) * 4) = pk.s;
        }
    } else {
        const int bx = blockIdx.x - nb_nrm;           // 0..127
        const int d0 = bx * 128;
        const int total = 128 * C;
        const float* src = reps + (size_t)d0 * C;
        for (int i = tid; i < total; i += 256)
            lds[i / C][i % C] = src[i];               // coalesced load
        __syncthreads();
        const int c = tid >> 3;                       // 0..31
        const int dsub = (tid & 7) * 16;              // 16 d per thread
        short* dstp = rt + (size_t)c * D + d0 + dsub;
        #pragma unroll
        for (int j0 = 0; j0 < 16; j0 += 4) {
            float v0, v1, v2, v3;
            if (c < C) {
                v0 = lds[dsub + j0 + 0][c]; v1 = lds[dsub + j0 + 1][c];
                v2 = lds[dsub + j0 + 2][c]; v3 = lds[dsub + j0 + 3][c];
            } else {
                float f = (c == C) ? 1.0f : 0.0f;     // ones column -> intensity
                v0 = v1 = v2 = v3 = f;
            }
            union { uint32_t u[2]; short4 s; } pk;
            pk.u[0] = cvt_pk_bf16(v0, v1);
            pk.u[1] = cvt_pk_bf16(v2, v3);
            *(short4*)(dstp + j0) = pk.s;             // coalesced store
        }
    }
}

// ---- fused: GEMM1 computes S^T via operand-swapped MFMA (A=En, B=Fn); the
// activated tile sits in 16x16x16 B-operand layout and feeds GEMM2
// echo^T += Rt_frag * a^T with NO LDS round-trip.
//
// SESSION LEDGER (final):
//  r9/r10/r16: extra-live-reg pipelining -> spill at 128 cap. DEAD.
//  r11 no-LDS direct-global  -> VMEM issue-bound (16 lines/load). DEAD.
//  r13 atomic epilogue       -> cross-XCD fabric traffic. DEAD.
//  r14 MT=256 @(256,2)       -> traffic halved, wall flat (lockstep).
//  r18 wave-private nobar    -> flat 72.5: rt-after-stage vmcnt(0) drain.
//  r19 rt-hoist              -> 65.3. Drain killed (counted vmcnt only).
//  r20 cooperative batch     -> 70: stage-service theory refuted. DEAD.
//  r21 cvt_pk @ reg slack    -> 46.8us, MfmaUtil 35%.
//  r22-24 mega cooperative   -> grid.sync does NOT give cross-XCD visibility
//      on gfx950 (absmax 0.52). Kernel boundaries are the only proven flush.
//  r25 vec reduce + cvt_pk prep -> 117.8us end-to-end (session best).
// r26 (this): T5 s_setprio around the MFMA clusters. m190's null was the
// barrier-LOCKSTEP structure; this kernel is barrier-free with free wave
// drift -> waves on a SIMD are at DIFFERENT phases (MFMA vs act-VALU vs
// stage), which is exactly T5's prerequisite. prio1 during GEMM1/GEMM2,
// prio0 during act/stage/waits. Zero registers, zero layout risk.
__global__ __launch_bounds__(256, 2) void fused_kernel(const short* __restrict__ Fn,
                                                       const short* __restrict__ En,
                                                       const short* __restrict__ Rt,
                                                       const int* __restrict__ pptr,
                                                       float* __restrict__ partial,
                                                       int N, int D, int C, int Dchunk) {
    __shared__ __align__(16) short lds_en[4][2][BDW * HDIM];   // per-wave dbuf, 64 KB

    const int tid  = threadIdx.x;
    const int lane = tid & 63;
    const int wv   = tid >> 6;
    const int q    = lane >> 4;
    const int l    = lane & 15;
    const int p    = pptr[0];

    const int Mbase = blockIdx.y * MT;
    const int dbase = blockIdx.x * Dchunk;

    const f32x4 zf = {0.0f, 0.0f, 0.0f, 0.0f};

    // Fn fragments (B-operand of GEMM1): B[k=ks*32+q*8+j][n=l] — de-swizzle in
    // the address. 4 f-tiles x 8 ks = 128 VGPR, resident for the whole kernel.
    bf16x8 afrag[4][8];
    #pragma unroll
    for (int fn = 0; fn < 4; ++fn) {
        const short* rowp = Fn + (size_t)(Mbase + wv * 64 + fn * 16 + l) * HDIM;
        #pragma unroll
        for (int ks = 0; ks < 8; ++ks)
            afrag[fn][ks] = *(const bf16x8*)(rowp + (((ks * 4 + q) ^ (l & 7)) << 3));
    }

    // echo^T accumulators: [f-tile][c-tile], C/D layout col=f(l), row=c(q*4+r)
    f32x4 echo_acc[4][2];
    #pragma unroll
    for (int fn = 0; fn < 4; ++fn) { echo_acc[fn][0] = zf; echo_acc[fn][1] = zf; }

    const int nwin = Dchunk / BDW;       // 32 wave-private windows

    // Wave-private stage: window it_ (16 En rows = 8KB) -> lds_en[wv][buf_].
    // One gload_lds(16B) covers 64 lanes x 16B = 1024B = 512 shorts.
    #define STAGE_W(buf_, it_)                                                      \
        {                                                                           \
            const short* gbase = En + (size_t)(dbase + (it_) * BDW) * HDIM + lane * 8;\
            as3_short* lbase = (as3_short*)(&lds_en[wv][buf_][0]);                  \
            _Pragma("unroll")                                                       \
            for (int i = 0; i < 8; ++i) {                                           \
                __builtin_amdgcn_global_load_lds((as1_short*)(gbase + i * 512),     \
                                                 lbase + i * 512, 16, 0, 0);        \
            }                                                                       \
        }

    const short* rtp = Rt + (size_t)l * D + q * 4;    // c-tile 0 row; +16*D for tile 1

    STAGE_W(0, 0)
    STAGE_W(1, 1)                        // 16 outstanding

    for (int it = 0; it < nwin; ++it) {
        const int buf = it & 1;

        // stage(it) landed: >=8 newer VMEM ops outstanding (stage(it+1)) ->
        // vmcnt(8) drains exactly through stage(it) without idling the queue.
        if (it < nwin - 1) {
            asm volatile("s_waitcnt vmcnt(8)" ::: "memory");
        } else {
            asm volatile("s_waitcnt vmcnt(0)" ::: "memory");   // peeled tail
        }
        __builtin_amdgcn_sched_barrier(0);

        const int d0 = dbase + it * BDW;

        // GEMM1: S^T tile 16(D) x 64(M), K=256, from the wave's own buffer.
        // T5: elevated priority while this wave drives the MFMA pipe.
        __builtin_amdgcn_s_setprio(1);
        f32x4 sT[4];
        #pragma unroll
        for (int fn = 0; fn < 4; ++fn) sT[fn] = zf;
        #pragma unroll
        for (int ks = 0; ks < 8; ++ks) {
            const int slot = (ks * 4 + q) ^ (l & 7);
            bf16x8 ef = *(const bf16x8*)(&lds_en[wv][buf][l * HDIM + slot * 8]);
            #pragma unroll
            for (int fn = 0; fn < 4; ++fn)
                sT[fn] = __builtin_amdgcn_mfma_f32_16x16x32_bf16(ef, afrag[fn][ks], sT[fn], 0, 0, 0);
        }
        __builtin_amdgcn_s_setprio(0);

        // r19: rt loads issued HERE — before the STAGE in program order (the
        // sched_barrier below pins them above it). GEMM2's wait is counted.
        bf16x4 rt0 = *(const bf16x4*)(rtp + d0);                  // c-tile 0
        bf16x4 rt1 = *(const bf16x4*)(rtp + (size_t)16 * D + d0); // c-tile 1

        // all 8 ds_reads consumed by GEMM1 -> lgkmcnt(0) is ~free; fences the
        // buffer against the overwrite below.
        asm volatile("s_waitcnt lgkmcnt(0)" ::: "memory");
        __builtin_amdgcn_sched_barrier(0);
        if (it + 2 < nwin) STAGE_W(buf, it + 2)

        // r21: activation via cvt_pk (16 mul + 8 cvt_pk per window), prio 0.
        bf16x4 pfrag[4];
        #pragma unroll
        for (int fn = 0; fn < 4; ++fn) {
            float a0, a1, a2, a3;
            {
                float s0 = sT[fn][0], s1 = sT[fn][1];
                float s2 = sT[fn][2], s3 = sT[fn][3];
                if (p == 3) {
                    a0 = s0 * s0 * s0; a1 = s1 * s1 * s1;
                    a2 = s2 * s2 * s2; a3 = s3 * s3 * s3;
                } else if (p == 1) {
                    a0 = s0; a1 = s1; a2 = s2; a3 = s3;
                } else if (p == 2) {
                    a0 = s0 * fabsf(s0); a1 = s1 * fabsf(s1);
                    a2 = s2 * fabsf(s2); a3 = s3 * fabsf(s3);
                } else {
                    a0 = copysignf(powf(fabsf(s0), (float)p), s0);
                    a1 = copysignf(powf(fabsf(s1), (float)p), s1);
                    a2 = copysignf(powf(fabsf(s2), (float)p), s2);
                    a3 = copysignf(powf(fabsf(s3), (float)p), s3);
                }
            }
            union { uint32_t u[2]; bf16x4 v; } pk;
            pk.u[0] = cvt_pk_bf16(a0, a1);
            pk.u[1] = cvt_pk_bf16(a2, a3);
            pfrag[fn] = pk.v;
        }

        // GEMM2: echo^T += Rt_frag(A) * a^T(B), 16x16x16, K=16 (this window).
        __builtin_amdgcn_s_setprio(1);
        #pragma unroll
        for (int fn = 0; fn < 4; ++fn) {
            echo_acc[fn][0] = __builtin_amdgcn_mfma_f32_16x16x16bf16_1k(rt0, pfrag[fn], echo_acc[fn][0], 0, 0, 0);
            echo_acc[fn][1] = __builtin_amdgcn_mfma_f32_16x16x16bf16_1k(rt1, pfrag[fn], echo_acc[fn][1], 0, 0, 0);
        }
        __builtin_amdgcn_s_setprio(0);
    }

    // Epilogue: echo^T C-layout (col f = l, rows c = ct*16 + q*4 + r) -> one
    // float4 store per (f-tile, c-tile); reduce kernel ignores c > C.
    #pragma unroll
    for (int fn = 0; fn < 4; ++fn) {
        const int grow = Mbase + wv * 64 + fn * 16 + l;
        float* rowp = partial + ((size_t)blockIdx.x * N + grow) * 32 + q * 4;
        *(f32x4*)(rowp)      = echo_acc[fn][0];
        *(f32x4*)(rowp + 16) = echo_acc[fn][1];
    }

    #undef STAGE_W
}

// ---- reduce: sum partials over splits; vectorized f32x4. One thread per
// (row, 4-col group); consecutive threads read consecutive 16B (coalesced).
__global__ __launch_bounds__(256) void reduce_kernel(const float* __restrict__ partial,
                                                     float* __restrict__ echo,
                                                     float* __restrict__ inten,
                                                     int N, int splits, int C) {
    const int t = blockIdx.x * 256 + threadIdx.x;     // N*8 threads
    const int row = t >> 3, g = t & 7;
    if (row >= N) return;
    const int c0 = g * 4;
    f32x4 s = {0.0f, 0.0f, 0.0f, 0.0f};
    const float* src = partial + (size_t)row * 32 + c0;
    #pragma unroll 8
    for (int k = 0; k < splits; ++k)
        s += *(const f32x4*)(src + (size_t)k * N * 32);
    #pragma unroll
    for (int j = 0; j < 4; ++j) {
        const int c = c0 + j;
        if (c < C)       echo[(size_t)row * C + c] = s[j];
        else if (c == C) inten[row] = s[j];
    }
}

extern "C" void kernel_launch(void* const* d_in, const int* in_sizes, int n_in,
                              void* d_out, int out_size, void* d_ws, size_t ws_size,
                              hipStream_t stream) {
    const int N = in_sizes[0] / HDIM;       // 4096
    const int D = in_sizes[1] / HDIM;       // 16384
    const int C = in_sizes[2] / D;          // 28

    const float* feat = (const float*)d_in[0];
    const float* exf  = (const float*)d_in[1];
    const float* reps = (const float*)d_in[2];
    const int*   p    = (const int*)d_in[3];

    short* Fn = (short*)d_ws;                          // [N][256] bf16 (swizzled)
    short* En = Fn + (size_t)N * HDIM;                 // [D][256] bf16 (swizzled)
    short* Rt = En + (size_t)D * HDIM;                 // [32][D] bf16 (col C = 1.0)
    float* partial = (float*)(Rt + (size_t)32 * D);    // [SPLITS][N][32] f32

    float* echo  = (float*)d_out;
    float* inten = echo + (size_t)N * C;

    const int nb_nrm = (N + D + RPB - 1) / RPB;
    hipLaunchKernelGGL(prep_kernel, dim3(nb_nrm + D / 128), dim3(256), 0, stream,
                       feat, exf, reps, Fn, Rt, N, N + D, D, C, nb_nrm);

    const int Dchunk = D / SPLITS;
    hipLaunchKernelGGL(fused_kernel, dim3(SPLITS, N / MT), dim3(256), 0, stream,
                       Fn, En, Rt, p, partial, N, D, C, Dchunk);

    hipLaunchKernelGGL(reduce_kernel, dim3(N * 8 / 256), dim3(256), 0, stream,
                       partial, echo, inten, N, SPLITS, C);
}

// Round 17
// 117.558 us; speedup vs baseline: 1.0033x; 1.0033x over previous
//
#include <hip/hip_runtime.h>
#include <cstdint>

#define HDIM 256
#define MT   256      // feature rows per block (4 waves x 64 rows)
#define BDW  16       // En rows per WAVE-PRIVATE window (one MFMA A-tile)
#define SPLITS 32
#define RPB  16       // rows per prep block (4 per wave)

typedef short bf16x8 __attribute__((ext_vector_type(8)));
typedef short bf16x4 __attribute__((ext_vector_type(4)));
typedef float f32x4  __attribute__((ext_vector_type(4)));

typedef const __attribute__((address_space(1))) short as1_short;
typedef __attribute__((address_space(3))) short as3_short;

// packed RNE f32->bf16 (r21-proven: -28% fused wall, absmax unchanged).
static __device__ __forceinline__ uint32_t cvt_pk_bf16(float lo, float hi) {
    uint32_t r;
    asm("v_cvt_pk_bf16_f32 %0, %1, %2" : "=v"(r) : "v"(lo), "v"(hi));
    return r;
}

// ---- prep (single dispatch):
//  blocks [0, nb_nrm)          : L2-normalize feature/ex_feature rows -> bf16,
//                                stored with XOR-16B-chunk swizzle; 4 rows/wave
//  blocks [nb_nrm, nb_nrm+128) : transpose class reps to Rt[32][D] (col C = 1.0
//                                -> intensity falls out of the echo GEMM)
__global__ __launch_bounds__(256) void prep_kernel(const float* __restrict__ fsrc,
                                                   const float* __restrict__ esrc,
                                                   const float* __restrict__ reps,
                                                   short* __restrict__ dst,
                                                   short* __restrict__ rt,
                                                   int N, int rows_total,
                                                   int D, int C, int nb_nrm) {
    __shared__ float lds[128][29];                    // +1 pad col
    const int tid = threadIdx.x;
    if ((int)blockIdx.x < nb_nrm) {
        int wv = tid >> 6;
        int lane = tid & 63;
        int row0 = blockIdx.x * RPB + wv * 4;
        #pragma unroll
        for (int rr = 0; rr < 4; ++rr) {
            int row = row0 + rr;
            if (row >= rows_total) continue;
            const float* src = (row < N) ? (fsrc + (size_t)row * HDIM)
                                         : (esrc + (size_t)(row - N) * HDIM);
            const float4 v = *(const float4*)(src + lane * 4);
            float ss = v.x * v.x + v.y * v.y + v.z * v.z + v.w * v.w;
            #pragma unroll
            for (int m = 1; m < 64; m <<= 1) ss += __shfl_xor(ss, m, 64);
            float scale = 1.0f / fmaxf(sqrtf(ss), 1e-12f);
            union { uint32_t u[2]; short4 s; } pk;
            pk.u[0] = cvt_pk_bf16(v.x * scale, v.y * scale);
            pk.u[1] = cvt_pk_bf16(v.z * scale, v.w * scale);
            int chunk = (lane >> 1) ^ (row & 7);      // swizzled 16B-chunk index
            *(short4*)(dst + (size_t)row * HDIM + chunk * 8 + (lane & 1) * 4) = pk.s;
        }
    } else {
        const int bx = blockIdx.x - nb_nrm;           // 0..127
        const int d0 = bx * 128;
        const int total = 128 * C;
        const float* src = reps + (size_t)d0 * C;
        for (int i = tid; i < total; i += 256)
            lds[i / C][i % C] = src[i];               // coalesced load
        __syncthreads();
        const int c = tid >> 3;                       // 0..31
        const int dsub = (tid & 7) * 16;              // 16 d per thread
        short* dstp = rt + (size_t)c * D + d0 + dsub;
        #pragma unroll
        for (int j0 = 0; j0 < 16; j0 += 4) {
            float v0, v1, v2, v3;
            if (c < C) {
                v0 = lds[dsub + j0 + 0][c]; v1 = lds[dsub + j0 + 1][c];
                v2 = lds[dsub + j0 + 2][c]; v3 = lds[dsub + j0 + 3][c];
            } else {
                float f = (c == C) ? 1.0f : 0.0f;     // ones column -> intensity
                v0 = v1 = v2 = v3 = f;
            }
            union { uint32_t u[2]; short4 s; } pk;
            pk.u[0] = cvt_pk_bf16(v0, v1);
            pk.u[1] = cvt_pk_bf16(v2, v3);
            *(short4*)(dstp + j0) = pk.s;             // coalesced store
        }
    }
}

// ---- fused: GEMM1 computes S^T via operand-swapped MFMA (A=En, B=Fn); the
// activated tile sits in 16x16x16 B-operand layout and feeds GEMM2
// echo^T += Rt_frag * a^T with NO LDS round-trip.
//
// SESSION LEDGER (final adjudication of every lever tried):
//  r9/r10/r16: extra-live-reg pipelining -> spill at 128 cap. DEAD.
//  r11 no-LDS direct-global  -> VMEM issue-bound (16 lines/load). DEAD.
//  r13 atomic epilogue       -> cross-XCD fabric traffic. DEAD.
//  r14 MT=256 @(256,2)       -> traffic/conflicts halved; enabler for r19/r21.
//  r18 wave-private nobar    -> flat 72.5: rt-after-stage vmcnt(0) drain.
//  r19 rt-hoist              -> 65.3. WIN: counted vmcnt only, no drains.
//  r20 cooperative batch     -> 70: stage-service theory refuted. DEAD.
//  r21 cvt_pk @ reg slack    -> 46.8us fused, MfmaUtil 35.5%. WIN.
//  r22-24 mega cooperative   -> grid.sync does NOT give cross-XCD visibility
//      on gfx950 (absmax 0.52). Kernel boundaries are the only proven flush.
//  r25 vec reduce + cvt_pk prep -> 117.8us end-to-end. SESSION BEST.
//  r26 T5 setprio            -> fused 53.2 (-13%): in a self-staging
//      barrier-free GEMM every wave carries all roles, so prio-tilting
//      starves other waves' stage/ds issue. REVERTED.
// This file == r25 (the verified best). Remaining fused stall (~25% at
// 2 waves/SIMD) requires >2 blocks/CU (impossible: 64KB LDS + ~150 live
// regs both cap at 2) or an accumulator-geometry redesign.
__global__ __launch_bounds__(256, 2) void fused_kernel(const short* __restrict__ Fn,
                                                       const short* __restrict__ En,
                                                       const short* __restrict__ Rt,
                                                       const int* __restrict__ pptr,
                                                       float* __restrict__ partial,
                                                       int N, int D, int C, int Dchunk) {
    __shared__ __align__(16) short lds_en[4][2][BDW * HDIM];   // per-wave dbuf, 64 KB

    const int tid  = threadIdx.x;
    const int lane = tid & 63;
    const int wv   = tid >> 6;
    const int q    = lane >> 4;
    const int l    = lane & 15;
    const int p    = pptr[0];

    const int Mbase = blockIdx.y * MT;
    const int dbase = blockIdx.x * Dchunk;

    const f32x4 zf = {0.0f, 0.0f, 0.0f, 0.0f};

    // Fn fragments (B-operand of GEMM1): B[k=ks*32+q*8+j][n=l] — de-swizzle in
    // the address. 4 f-tiles x 8 ks = 128 VGPR, resident for the whole kernel.
    bf16x8 afrag[4][8];
    #pragma unroll
    for (int fn = 0; fn < 4; ++fn) {
        const short* rowp = Fn + (size_t)(Mbase + wv * 64 + fn * 16 + l) * HDIM;
        #pragma unroll
        for (int ks = 0; ks < 8; ++ks)
            afrag[fn][ks] = *(const bf16x8*)(rowp + (((ks * 4 + q) ^ (l & 7)) << 3));
    }

    // echo^T accumulators: [f-tile][c-tile], C/D layout col=f(l), row=c(q*4+r)
    f32x4 echo_acc[4][2];
    #pragma unroll
    for (int fn = 0; fn < 4; ++fn) { echo_acc[fn][0] = zf; echo_acc[fn][1] = zf; }

    const int nwin = Dchunk / BDW;       // 32 wave-private windows

    // Wave-private stage: window it_ (16 En rows = 8KB) -> lds_en[wv][buf_].
    // One gload_lds(16B) covers 64 lanes x 16B = 1024B = 512 shorts.
    #define STAGE_W(buf_, it_)                                                      \
        {                                                                           \
            const short* gbase = En + (size_t)(dbase + (it_) * BDW) * HDIM + lane * 8;\
            as3_short* lbase = (as3_short*)(&lds_en[wv][buf_][0]);                  \
            _Pragma("unroll")                                                       \
            for (int i = 0; i < 8; ++i) {                                           \
                __builtin_amdgcn_global_load_lds((as1_short*)(gbase + i * 512),     \
                                                 lbase + i * 512, 16, 0, 0);        \
            }                                                                       \
        }

    const short* rtp = Rt + (size_t)l * D + q * 4;    // c-tile 0 row; +16*D for tile 1

    STAGE_W(0, 0)
    STAGE_W(1, 1)                        // 16 outstanding

    for (int it = 0; it < nwin; ++it) {
        const int buf = it & 1;

        // stage(it) landed: >=8 newer VMEM ops outstanding (stage(it+1)) ->
        // vmcnt(8) drains exactly through stage(it) without idling the queue.
        if (it < nwin - 1) {
            asm volatile("s_waitcnt vmcnt(8)" ::: "memory");
        } else {
            asm volatile("s_waitcnt vmcnt(0)" ::: "memory");   // peeled tail
        }
        __builtin_amdgcn_sched_barrier(0);

        const int d0 = dbase + it * BDW;

        // GEMM1: S^T tile 16(D) x 64(M), K=256, from the wave's own buffer.
        f32x4 sT[4];
        #pragma unroll
        for (int fn = 0; fn < 4; ++fn) sT[fn] = zf;
        #pragma unroll
        for (int ks = 0; ks < 8; ++ks) {
            const int slot = (ks * 4 + q) ^ (l & 7);
            bf16x8 ef = *(const bf16x8*)(&lds_en[wv][buf][l * HDIM + slot * 8]);
            #pragma unroll
            for (int fn = 0; fn < 4; ++fn)
                sT[fn] = __builtin_amdgcn_mfma_f32_16x16x32_bf16(ef, afrag[fn][ks], sT[fn], 0, 0, 0);
        }

        // r19: rt loads issued HERE — before the STAGE in program order (the
        // sched_barrier below pins them above it). GEMM2's wait is counted.
        bf16x4 rt0 = *(const bf16x4*)(rtp + d0);                  // c-tile 0
        bf16x4 rt1 = *(const bf16x4*)(rtp + (size_t)16 * D + d0); // c-tile 1

        // all 8 ds_reads consumed by GEMM1 -> lgkmcnt(0) is ~free; fences the
        // buffer against the overwrite below.
        asm volatile("s_waitcnt lgkmcnt(0)" ::: "memory");
        __builtin_amdgcn_sched_barrier(0);
        if (it + 2 < nwin) STAGE_W(buf, it + 2)

        // r21: activation via cvt_pk (16 mul + 8 cvt_pk per window)
        bf16x4 pfrag[4];
        #pragma unroll
        for (int fn = 0; fn < 4; ++fn) {
            float a0, a1, a2, a3;
            {
                float s0 = sT[fn][0], s1 = sT[fn][1];
                float s2 = sT[fn][2], s3 = sT[fn][3];
                if (p == 3) {
                    a0 = s0 * s0 * s0; a1 = s1 * s1 * s1;
                    a2 = s2 * s2 * s2; a3 = s3 * s3 * s3;
                } else if (p == 1) {
                    a0 = s0; a1 = s1; a2 = s2; a3 = s3;
                } else if (p == 2) {
                    a0 = s0 * fabsf(s0); a1 = s1 * fabsf(s1);
                    a2 = s2 * fabsf(s2); a3 = s3 * fabsf(s3);
                } else {
                    a0 = copysignf(powf(fabsf(s0), (float)p), s0);
                    a1 = copysignf(powf(fabsf(s1), (float)p), s1);
                    a2 = copysignf(powf(fabsf(s2), (float)p), s2);
                    a3 = copysignf(powf(fabsf(s3), (float)p), s3);
                }
            }
            union { uint32_t u[2]; bf16x4 v; } pk;
            pk.u[0] = cvt_pk_bf16(a0, a1);
            pk.u[1] = cvt_pk_bf16(a2, a3);
            pfrag[fn] = pk.v;
        }

        // GEMM2: echo^T += Rt_frag(A) * a^T(B), 16x16x16, K=16 (this window)
        #pragma unroll
        for (int fn = 0; fn < 4; ++fn) {
            echo_acc[fn][0] = __builtin_amdgcn_mfma_f32_16x16x16bf16_1k(rt0, pfrag[fn], echo_acc[fn][0], 0, 0, 0);
            echo_acc[fn][1] = __builtin_amdgcn_mfma_f32_16x16x16bf16_1k(rt1, pfrag[fn], echo_acc[fn][1], 0, 0, 0);
        }
    }

    // Epilogue: echo^T C-layout (col f = l, rows c = ct*16 + q*4 + r) -> one
    // float4 store per (f-tile, c-tile); reduce kernel ignores c > C.
    #pragma unroll
    for (int fn = 0; fn < 4; ++fn) {
        const int grow = Mbase + wv * 64 + fn * 16 + l;
        float* rowp = partial + ((size_t)blockIdx.x * N + grow) * 32 + q * 4;
        *(f32x4*)(rowp)      = echo_acc[fn][0];
        *(f32x4*)(rowp + 16) = echo_acc[fn][1];
    }

    #undef STAGE_W
}

// ---- reduce: sum partials over splits; vectorized f32x4. One thread per
// (row, 4-col group); consecutive threads read consecutive 16B (coalesced).
__global__ __launch_bounds__(256) void reduce_kernel(const float* __restrict__ partial,
                                                     float* __restrict__ echo,
                                                     float* __restrict__ inten,
                                                     int N, int splits, int C) {
    const int t = blockIdx.x * 256 + threadIdx.x;     // N*8 threads
    const int row = t >> 3, g = t & 7;
    if (row >= N) return;
    const int c0 = g * 4;
    f32x4 s = {0.0f, 0.0f, 0.0f, 0.0f};
    const float* src = partial + (size_t)row * 32 + c0;
    #pragma unroll 8
    for (int k = 0; k < splits; ++k)
        s += *(const f32x4*)(src + (size_t)k * N * 32);
    #pragma unroll
    for (int j = 0; j < 4; ++j) {
        const int c = c0 + j;
        if (c < C)       echo[(size_t)row * C + c] = s[j];
        else if (c == C) inten[row] = s[j];
    }
}

extern "C" void kernel_launch(void* const* d_in, const int* in_sizes, int n_in,
                              void* d_out, int out_size, void* d_ws, size_t ws_size,
                              hipStream_t stream) {
    const int N = in_sizes[0] / HDIM;       // 4096
    const int D = in_sizes[1] / HDIM;       // 16384
    const int C = in_sizes[2] / D;          // 28

    const float* feat = (const float*)d_in[0];
    const float* exf  = (const float*)d_in[1];
    const float* reps = (const float*)d_in[2];
    const int*   p    = (const int*)d_in[3];

    short* Fn = (short*)d_ws;                          // [N][256] bf16 (swizzled)
    short* En = Fn + (size_t)N * HDIM;                 // [D][256] bf16 (swizzled)
    short* Rt = En + (size_t)D * HDIM;                 // [32][D] bf16 (col C = 1.0)
    float* partial = (float*)(Rt + (size_t)32 * D);    // [SPLITS][N][32] f32

    float* echo  = (float*)d_out;
    float* inten = echo + (size_t)N * C;

    const int nb_nrm = (N + D + RPB - 1) / RPB;
    hipLaunchKernelGGL(prep_kernel, dim3(nb_nrm + D / 128), dim3(256), 0, stream,
                       feat, exf, reps, Fn, Rt, N, N + D, D, C, nb_nrm);

    const int Dchunk = D / SPLITS;
    hipLaunchKernelGGL(fused_kernel, dim3(SPLITS, N / MT), dim3(256), 0, stream,
                       Fn, En, Rt, p, partial, N, D, C, Dchunk);

    hipLaunchKernelGGL(reduce_kernel, dim3(N * 8 / 256), dim3(256), 0, stream,
                       partial, echo, inten, N, SPLITS, C);
}

// Round 18
// 116.995 us; speedup vs baseline: 1.0082x; 1.0048x over previous
//
#include <hip/hip_runtime.h>
#include <cstdint>

#define HDIM 256
#define MT   256      // feature rows per block (4 waves x 64 rows)
#define BDW  16       // En rows per WAVE-PRIVATE window (one MFMA A-tile)
#define SPLITS 32
#define RPB  16       // rows per prep block (4 per wave)

typedef short bf16x8 __attribute__((ext_vector_type(8)));
typedef short bf16x4 __attribute__((ext_vector_type(4)));
typedef float f32x4  __attribute__((ext_vector_type(4)));

typedef const __attribute__((address_space(1))) short as1_short;
typedef __attribute__((address_space(3))) short as3_short;

// packed RNE f32->bf16 (r21-proven: -28% fused wall, absmax unchanged).
static __device__ __forceinline__ uint32_t cvt_pk_bf16(float lo, float hi) {
    uint32_t r;
    asm("v_cvt_pk_bf16_f32 %0, %1, %2" : "=v"(r) : "v"(lo), "v"(hi));
    return r;
}

// ---- prep (single dispatch):
//  blocks [0, nb_nrm)          : L2-normalize feature/ex_feature rows -> bf16,
//                                stored with XOR-16B-chunk swizzle; 4 rows/wave
//  blocks [nb_nrm, nb_nrm+128) : transpose class reps into TILED Rt (r28):
//                                T[t][c][s] with t=d>>4, s=d&15 (col C = 1.0
//                                -> intensity falls out of the echo GEMM).
//                                Tiling makes the fused kernel's per-window
//                                rt fragment a coalesced 512B read (8 full
//                                lines) instead of a 16-line row-scatter.
__global__ __launch_bounds__(256) void prep_kernel(const float* __restrict__ fsrc,
                                                   const float* __restrict__ esrc,
                                                   const float* __restrict__ reps,
                                                   short* __restrict__ dst,
                                                   short* __restrict__ rt,
                                                   int N, int rows_total,
                                                   int D, int C, int nb_nrm) {
    __shared__ float lds[128][29];                    // +1 pad col
    const int tid = threadIdx.x;
    if ((int)blockIdx.x < nb_nrm) {
        int wv = tid >> 6;
        int lane = tid & 63;
        int row0 = blockIdx.x * RPB + wv * 4;
        #pragma unroll
        for (int rr = 0; rr < 4; ++rr) {
            int row = row0 + rr;
            if (row >= rows_total) continue;
            const float* src = (row < N) ? (fsrc + (size_t)row * HDIM)
                                         : (esrc + (size_t)(row - N) * HDIM);
            const float4 v = *(const float4*)(src + lane * 4);
            float ss = v.x * v.x + v.y * v.y + v.z * v.z + v.w * v.w;
            #pragma unroll
            for (int m = 1; m < 64; m <<= 1) ss += __shfl_xor(ss, m, 64);
            float scale = 1.0f / fmaxf(sqrtf(ss), 1e-12f);
            union { uint32_t u[2]; short4 s; } pk;
            pk.u[0] = cvt_pk_bf16(v.x * scale, v.y * scale);
            pk.u[1] = cvt_pk_bf16(v.z * scale, v.w * scale);
            int chunk = (lane >> 1) ^ (row & 7);      // swizzled 16B-chunk index
            *(short4*)(dst + (size_t)row * HDIM + chunk * 8 + (lane & 1) * 4) = pk.s;
        }
    } else {
        const int bx = blockIdx.x - nb_nrm;           // 0..127
        const int d0 = bx * 128;
        const int total = 128 * C;
        const float* src = reps + (size_t)d0 * C;
        for (int i = tid; i < total; i += 256)
            lds[i / C][i % C] = src[i];               // coalesced load
        __syncthreads();
        const int c = tid >> 3;                       // 0..31
        const int dsub = (tid & 7) * 16;              // 16 d per thread = 1 tile
        // r28 tiled store: Rt_old[c][d] lives at T[d>>4]*512 + c*16 + (d&15).
        // dsub is a multiple of 16, so this thread's 16 d-values are exactly
        // tile (d0+dsub)>>4, row c.
        short* dstp = rt + ((size_t)(d0 + dsub) >> 4) * 512 + c * 16;
        #pragma unroll
        for (int j0 = 0; j0 < 16; j0 += 4) {
            float v0, v1, v2, v3;
            if (c < C) {
                v0 = lds[dsub + j0 + 0][c]; v1 = lds[dsub + j0 + 1][c];
                v2 = lds[dsub + j0 + 2][c]; v3 = lds[dsub + j0 + 3][c];
            } else {
                float f = (c == C) ? 1.0f : 0.0f;     // ones column -> intensity
                v0 = v1 = v2 = v3 = f;
            }
            union { uint32_t u[2]; short4 s; } pk;
            pk.u[0] = cvt_pk_bf16(v0, v1);
            pk.u[1] = cvt_pk_bf16(v2, v3);
            *(short4*)(dstp + j0) = pk.s;
        }
    }
}

// ---- fused: GEMM1 computes S^T via operand-swapped MFMA (A=En, B=Fn); the
// activated tile sits in 16x16x16 B-operand layout and feeds GEMM2
// echo^T += Rt_frag * a^T with NO LDS round-trip.
//
// SESSION LEDGER (adjudication of every lever):
//  r9/r10/r16: extra-live-reg pipelining -> spill at 128 cap. DEAD.
//  r11 no-LDS direct-global  -> VMEM issue-bound (16 lines/load). DEAD.
//  r13 atomic epilogue       -> cross-XCD fabric traffic. DEAD.
//  r14 MT=256 @(256,2)       -> traffic/conflicts halved; enabler for r19/r21.
//  r18 wave-private nobar    -> flat 72.5: rt-after-stage vmcnt(0) drain.
//  r19 rt-hoist              -> 65.3. WIN: counted vmcnt only, no drains.
//  r20 cooperative batch     -> 70: barrier re-bunching > stage savings. DEAD.
//  r21 cvt_pk @ reg slack    -> 46.8us fused, MfmaUtil 35.5%. WIN.
//  r22-24 mega cooperative   -> grid.sync does NOT give cross-XCD visibility
//      on gfx950 (absmax 0.52). Kernel boundaries are the only proven flush.
//  r25 vec reduce + cvt_pk prep -> 117.8us end-to-end.
//  r26 T5 setprio            -> fused 53.2 (-13%): self-staging waves carry
//      all roles; prio-tilting starves other waves' stage/ds issue. DEAD.
// r28 (this): the last register-neutral VMEM lever. rt loads were 16-line
// row-scatters (lane l reads Rt[l][...], the r11-proven expensive class) —
// 2/window/wave = ~20% of VMEM line traffic for 1.5% of bytes. Tiled Rt
// (T[d>>4][c][d&15]) makes each rt fragment one coalesced 512B region
// (8 fully-used lines): rt0 = tile base + l*16+q*4, rt1 = +256. Values
// delivered are bit-identical to r25's.
__global__ __launch_bounds__(256, 2) void fused_kernel(const short* __restrict__ Fn,
                                                       const short* __restrict__ En,
                                                       const short* __restrict__ Rt,
                                                       const int* __restrict__ pptr,
                                                       float* __restrict__ partial,
                                                       int N, int D, int C, int Dchunk) {
    __shared__ __align__(16) short lds_en[4][2][BDW * HDIM];   // per-wave dbuf, 64 KB

    const int tid  = threadIdx.x;
    const int lane = tid & 63;
    const int wv   = tid >> 6;
    const int q    = lane >> 4;
    const int l    = lane & 15;
    const int p    = pptr[0];

    const int Mbase = blockIdx.y * MT;
    const int dbase = blockIdx.x * Dchunk;

    const f32x4 zf = {0.0f, 0.0f, 0.0f, 0.0f};

    // Fn fragments (B-operand of GEMM1): B[k=ks*32+q*8+j][n=l] — de-swizzle in
    // the address. 4 f-tiles x 8 ks = 128 VGPR, resident for the whole kernel.
    bf16x8 afrag[4][8];
    #pragma unroll
    for (int fn = 0; fn < 4; ++fn) {
        const short* rowp = Fn + (size_t)(Mbase + wv * 64 + fn * 16 + l) * HDIM;
        #pragma unroll
        for (int ks = 0; ks < 8; ++ks)
            afrag[fn][ks] = *(const bf16x8*)(rowp + (((ks * 4 + q) ^ (l & 7)) << 3));
    }

    // echo^T accumulators: [f-tile][c-tile], C/D layout col=f(l), row=c(q*4+r)
    f32x4 echo_acc[4][2];
    #pragma unroll
    for (int fn = 0; fn < 4; ++fn) { echo_acc[fn][0] = zf; echo_acc[fn][1] = zf; }

    const int nwin = Dchunk / BDW;       // 32 wave-private windows

    // Wave-private stage: window it_ (16 En rows = 8KB) -> lds_en[wv][buf_].
    // One gload_lds(16B) covers 64 lanes x 16B = 1024B = 512 shorts.
    #define STAGE_W(buf_, it_)                                                      \
        {                                                                           \
            const short* gbase = En + (size_t)(dbase + (it_) * BDW) * HDIM + lane * 8;\
            as3_short* lbase = (as3_short*)(&lds_en[wv][buf_][0]);                  \
            _Pragma("unroll")                                                       \
            for (int i = 0; i < 8; ++i) {                                           \
                __builtin_amdgcn_global_load_lds((as1_short*)(gbase + i * 512),     \
                                                 lbase + i * 512, 16, 0, 0);        \
            }                                                                       \
        }

    // r28: lane base inside a 512-element Rt tile (rt0 = rows 0-15 half,
    // rt1 = +256 for rows 16-31).
    const short* rtp = Rt + (size_t)l * 16 + q * 4;

    STAGE_W(0, 0)
    STAGE_W(1, 1)                        // 16 outstanding

    for (int it = 0; it < nwin; ++it) {
        const int buf = it & 1;

        // stage(it) landed: >=8 newer VMEM ops outstanding (stage(it+1)) ->
        // vmcnt(8) drains exactly through stage(it) without idling the queue.
        if (it < nwin - 1) {
            asm volatile("s_waitcnt vmcnt(8)" ::: "memory");
        } else {
            asm volatile("s_waitcnt vmcnt(0)" ::: "memory");   // peeled tail
        }
        __builtin_amdgcn_sched_barrier(0);

        const int d0 = dbase + it * BDW;

        // GEMM1: S^T tile 16(D) x 64(M), K=256, from the wave's own buffer.
        f32x4 sT[4];
        #pragma unroll
        for (int fn = 0; fn < 4; ++fn) sT[fn] = zf;
        #pragma unroll
        for (int ks = 0; ks < 8; ++ks) {
            const int slot = (ks * 4 + q) ^ (l & 7);
            bf16x8 ef = *(const bf16x8*)(&lds_en[wv][buf][l * HDIM + slot * 8]);
            #pragma unroll
            for (int fn = 0; fn < 4; ++fn)
                sT[fn] = __builtin_amdgcn_mfma_f32_16x16x32_bf16(ef, afrag[fn][ks], sT[fn], 0, 0, 0);
        }

        // r19: rt loads issued HERE — before the STAGE in program order (the
        // sched_barrier below pins them above it). GEMM2's wait is counted.
        // r28: coalesced tile reads (one 512B region per load, 8 full lines).
        const short* rtw = rtp + ((size_t)(d0 >> 4)) * 512;
        bf16x4 rt0 = *(const bf16x4*)(rtw);                       // c rows 0-15
        bf16x4 rt1 = *(const bf16x4*)(rtw + 256);                 // c rows 16-31

        // all 8 ds_reads consumed by GEMM1 -> lgkmcnt(0) is ~free; fences the
        // buffer against the overwrite below.
        asm volatile("s_waitcnt lgkmcnt(0)" ::: "memory");
        __builtin_amdgcn_sched_barrier(0);
        if (it + 2 < nwin) STAGE_W(buf, it + 2)

        // r21: activation via cvt_pk (16 mul + 8 cvt_pk per window)
        bf16x4 pfrag[4];
        #pragma unroll
        for (int fn = 0; fn < 4; ++fn) {
            float a0, a1, a2, a3;
            {
                float s0 = sT[fn][0], s1 = sT[fn][1];
                float s2 = sT[fn][2], s3 = sT[fn][3];
                if (p == 3) {
                    a0 = s0 * s0 * s0; a1 = s1 * s1 * s1;
                    a2 = s2 * s2 * s2; a3 = s3 * s3 * s3;
                } else if (p == 1) {
                    a0 = s0; a1 = s1; a2 = s2; a3 = s3;
                } else if (p == 2) {
                    a0 = s0 * fabsf(s0); a1 = s1 * fabsf(s1);
                    a2 = s2 * fabsf(s2); a3 = s3 * fabsf(s3);
                } else {
                    a0 = copysignf(powf(fabsf(s0), (float)p), s0);
                    a1 = copysignf(powf(fabsf(s1), (float)p), s1);
                    a2 = copysignf(powf(fabsf(s2), (float)p), s2);
                    a3 = copysignf(powf(fabsf(s3), (float)p), s3);
                }
            }
            union { uint32_t u[2]; bf16x4 v; } pk;
            pk.u[0] = cvt_pk_bf16(a0, a1);
            pk.u[1] = cvt_pk_bf16(a2, a3);
            pfrag[fn] = pk.v;
        }

        // GEMM2: echo^T += Rt_frag(A) * a^T(B), 16x16x16, K=16 (this window)
        #pragma unroll
        for (int fn = 0; fn < 4; ++fn) {
            echo_acc[fn][0] = __builtin_amdgcn_mfma_f32_16x16x16bf16_1k(rt0, pfrag[fn], echo_acc[fn][0], 0, 0, 0);
            echo_acc[fn][1] = __builtin_amdgcn_mfma_f32_16x16x16bf16_1k(rt1, pfrag[fn], echo_acc[fn][1], 0, 0, 0);
        }
    }

    // Epilogue: echo^T C-layout (col f = l, rows c = ct*16 + q*4 + r) -> one
    // float4 store per (f-tile, c-tile); reduce kernel ignores c > C.
    #pragma unroll
    for (int fn = 0; fn < 4; ++fn) {
        const int grow = Mbase + wv * 64 + fn * 16 + l;
        float* rowp = partial + ((size_t)blockIdx.x * N + grow) * 32 + q * 4;
        *(f32x4*)(rowp)      = echo_acc[fn][0];
        *(f32x4*)(rowp + 16) = echo_acc[fn][1];
    }

    #undef STAGE_W
}

// ---- reduce: sum partials over splits; vectorized f32x4. One thread per
// (row, 4-col group); consecutive threads read consecutive 16B (coalesced).
__global__ __launch_bounds__(256) void reduce_kernel(const float* __restrict__ partial,
                                                     float* __restrict__ echo,
                                                     float* __restrict__ inten,
                                                     int N, int splits, int C) {
    const int t = blockIdx.x * 256 + threadIdx.x;     // N*8 threads
    const int row = t >> 3, g = t & 7;
    if (row >= N) return;
    const int c0 = g * 4;
    f32x4 s = {0.0f, 0.0f, 0.0f, 0.0f};
    const float* src = partial + (size_t)row * 32 + c0;
    #pragma unroll 8
    for (int k = 0; k < splits; ++k)
        s += *(const f32x4*)(src + (size_t)k * N * 32);
    #pragma unroll
    for (int j = 0; j < 4; ++j) {
        const int c = c0 + j;
        if (c < C)       echo[(size_t)row * C + c] = s[j];
        else if (c == C) inten[row] = s[j];
    }
}

extern "C" void kernel_launch(void* const* d_in, const int* in_sizes, int n_in,
                              void* d_out, int out_size, void* d_ws, size_t ws_size,
                              hipStream_t stream) {
    const int N = in_sizes[0] / HDIM;       // 4096
    const int D = in_sizes[1] / HDIM;       // 16384
    const int C = in_sizes[2] / D;          // 28

    const float* feat = (const float*)d_in[0];
    const float* exf  = (const float*)d_in[1];
    const float* reps = (const float*)d_in[2];
    const int*   p    = (const int*)d_in[3];

    short* Fn = (short*)d_ws;                          // [N][256] bf16 (swizzled)
    short* En = Fn + (size_t)N * HDIM;                 // [D][256] bf16 (swizzled)
    short* Rt = En + (size_t)D * HDIM;                 // [D/16][32][16] bf16 tiles
    float* partial = (float*)(Rt + (size_t)32 * D);    // [SPLITS][N][32] f32

    float* echo  = (float*)d_out;
    float* inten = echo + (size_t)N * C;

    const int nb_nrm = (N + D + RPB - 1) / RPB;
    hipLaunchKernelGGL(prep_kernel, dim3(nb_nrm + D / 128), dim3(256), 0, stream,
                       feat, exf, reps, Fn, Rt, N, N + D, D, C, nb_nrm);

    const int Dchunk = D / SPLITS;
    hipLaunchKernelGGL(fused_kernel, dim3(SPLITS, N / MT), dim3(256), 0, stream,
                       Fn, En, Rt, p, partial, N, D, C, Dchunk);

    hipLaunchKernelGGL(reduce_kernel, dim3(N * 8 / 256), dim3(256), 0, stream,
                       partial, echo, inten, N, SPLITS, C);
}